// Round 4
// baseline (1500.011 us; speedup 1.0000x reference)
//
#include <hip/hip_runtime.h>
#include <hip/hip_bf16.h>
#include <stdint.h>
#include <math.h>

typedef __bf16 bf16;
typedef __bf16 bf16x4 __attribute__((ext_vector_type(4)));
typedef __bf16 bf16x8 __attribute__((ext_vector_type(8)));
typedef float  f32x4  __attribute__((ext_vector_type(4)));

#define HIDDEN 4096
#define NH     32
#define NKV    8
#define HD     128
#define SEQ    2048
#define BATCH  2
#define NTOK   (BATCH*SEQ)   // 4096
#define QDIM   (NH*HD)       // 4096
#define KVDIM  (NKV*HD)      // 1024

#define NEGBIG (-3.0e38f)

// ---------------------------------------------------------------------------
// GEMM: C[m][n] = sum_k A[m][k] * B[n][k]   (A: MxK row-major, B: NxK row-major)
// 128x128 tile, BK=32, 4 waves 2x2, mfma_f32_16x16x32_bf16.
// A32/B32: operand is fp32 in global (converted to bf16 during LDS staging).
// F32OUT : C written as fp32 (for d_out).   TRANSV: write C^T in vt layout.
// ---------------------------------------------------------------------------
template<bool A32, bool B32, bool TRANSV, bool F32OUT>
__global__ __launch_bounds__(256)
void gemm_bt(const void* __restrict__ Av, const void* __restrict__ Bv,
             void* __restrict__ Cv, int M, int N, int K)
{
    __shared__ bf16 sA[128*32];
    __shared__ bf16 sB[128*32];

    const int tid  = threadIdx.x;
    const int wave = tid >> 6;
    const int lane = tid & 63;
    const int l15  = lane & 15;
    const int quad = lane >> 4;
    const int m_blk = blockIdx.y * 128;
    const int n_blk = blockIdx.x * 128;
    const int wm = (wave >> 1) * 64;
    const int wn = (wave & 1) * 64;

    f32x4 acc[4][4] = {};

    const int srow = tid >> 1;          // 0..127
    const int scol = (tid & 1) * 16;    // 0 or 16

    const float* gA32 = (const float*)Av + (size_t)(m_blk + srow) * K + scol;
    const bf16*  gA16 = (const bf16*) Av + (size_t)(m_blk + srow) * K + scol;
    const float* gB32 = (const float*)Bv + (size_t)(n_blk + srow) * K + scol;
    const bf16*  gB16 = (const bf16*) Bv + (size_t)(n_blk + srow) * K + scol;

    for (int k0 = 0; k0 < K; k0 += 32) {
        // global loads into registers first (overlap with prior compute)
        bf16x8 a0, a1, b0, b1;
        if constexpr (A32) {
            f32x4 f0 = *(const f32x4*)(gA32 + k0);
            f32x4 f1 = *(const f32x4*)(gA32 + k0 + 4);
            f32x4 f2 = *(const f32x4*)(gA32 + k0 + 8);
            f32x4 f3 = *(const f32x4*)(gA32 + k0 + 12);
            #pragma unroll
            for (int j = 0; j < 4; ++j) { a0[j] = (bf16)f0[j]; a0[4+j] = (bf16)f1[j];
                                          a1[j] = (bf16)f2[j]; a1[4+j] = (bf16)f3[j]; }
        } else {
            a0 = *(const bf16x8*)(gA16 + k0);
            a1 = *(const bf16x8*)(gA16 + k0 + 8);
        }
        if constexpr (B32) {
            f32x4 f0 = *(const f32x4*)(gB32 + k0);
            f32x4 f1 = *(const f32x4*)(gB32 + k0 + 4);
            f32x4 f2 = *(const f32x4*)(gB32 + k0 + 8);
            f32x4 f3 = *(const f32x4*)(gB32 + k0 + 12);
            #pragma unroll
            for (int j = 0; j < 4; ++j) { b0[j] = (bf16)f0[j]; b0[4+j] = (bf16)f1[j];
                                          b1[j] = (bf16)f2[j]; b1[4+j] = (bf16)f3[j]; }
        } else {
            b0 = *(const bf16x8*)(gB16 + k0);
            b1 = *(const bf16x8*)(gB16 + k0 + 8);
        }

        __syncthreads();   // previous iteration's readers done
        *(bf16x8*)(sA + srow*32 + scol)     = a0;
        *(bf16x8*)(sA + srow*32 + scol + 8) = a1;
        *(bf16x8*)(sB + srow*32 + scol)     = b0;
        *(bf16x8*)(sB + srow*32 + scol + 8) = b1;
        __syncthreads();   // writes visible to all

        bf16x8 af[4], bfr[4];
        #pragma unroll
        for (int mi = 0; mi < 4; ++mi)
            af[mi] = *(const bf16x8*)(sA + (wm + mi*16 + l15)*32 + quad*8);
        #pragma unroll
        for (int ni = 0; ni < 4; ++ni)
            bfr[ni] = *(const bf16x8*)(sB + (wn + ni*16 + l15)*32 + quad*8);
        #pragma unroll
        for (int mi = 0; mi < 4; ++mi)
            #pragma unroll
            for (int ni = 0; ni < 4; ++ni)
                acc[mi][ni] = __builtin_amdgcn_mfma_f32_16x16x32_bf16(
                                  af[mi], bfr[ni], acc[mi][ni], 0, 0, 0);
    }

    #pragma unroll
    for (int mi = 0; mi < 4; ++mi) {
        #pragma unroll
        for (int ni = 0; ni < 4; ++ni) {
            const int col = n_blk + wn + ni*16 + l15;
            if constexpr (TRANSV) {
                const int row0 = m_blk + wm + mi*16 + quad*4;
                const int bb = row0 >> 11;          // /SEQ
                const int ss = row0 & (SEQ - 1);
                bf16x4 pk;
                #pragma unroll
                for (int r = 0; r < 4; ++r) pk[r] = (bf16)acc[mi][ni][r];
                *(bf16x4*)((bf16*)Cv + ((size_t)bb * KVDIM + col) * SEQ + ss) = pk;
            } else if constexpr (F32OUT) {
                #pragma unroll
                for (int r = 0; r < 4; ++r) {
                    const int row = m_blk + wm + mi*16 + quad*4 + r;
                    ((float*)Cv)[(size_t)row * N + col] = acc[mi][ni][r];
                }
            } else {
                #pragma unroll
                for (int r = 0; r < 4; ++r) {
                    const int row = m_blk + wm + mi*16 + quad*4 + r;
                    ((bf16*)Cv)[(size_t)row * N + col] = (bf16)acc[mi][ni][r];
                }
            }
        }
    }
}

// ---------------------------------------------------------------------------
// Per-head LayerNorm + RoPE, in place on bf16 workspace. One wave per
// (token, head); lane j holds dims j and j+64 (the RoPE pair). w is fp32.
// ---------------------------------------------------------------------------
__global__ __launch_bounds__(256)
void ln_rope(bf16* __restrict__ buf, const float* __restrict__ w,
             const int* __restrict__ pos, int nh)
{
    const int id   = blockIdx.x * 4 + (threadIdx.x >> 6);
    const int lane = threadIdx.x & 63;
    const int t  = id / nh;
    const int hh = id - t * nh;

    bf16* p = buf + (size_t)t * nh * HD + hh * HD;
    float x1 = (float)p[lane];
    float x2 = (float)p[lane + 64];

    float s1 = x1 + x2, s2 = x1*x1 + x2*x2;
    #pragma unroll
    for (int m = 1; m < 64; m <<= 1) {
        s1 += __shfl_xor(s1, m);
        s2 += __shfl_xor(s2, m);
    }
    const float mean = s1 * (1.0f/128.0f);
    const float var  = s2 * (1.0f/128.0f) - mean*mean;
    const float rs   = rsqrtf(fmaxf(var, 0.0f) + 1e-5f);

    const float w1 = w[hh*HD + lane];
    const float w2 = w[hh*HD + lane + 64];
    const float xn1 = (x1 - mean) * rs * w1;
    const float xn2 = (x2 - mean) * rs * w2;

    const int s = t & (SEQ - 1);
    // inv_freq = 10000^(-lane/64) = exp(-lane * ln(10000)/64)
    const float ang = (float)pos[s] * __expf(-(float)lane * (9.210340371976184f/64.0f));
    const float c = cosf(ang), sn = sinf(ang);

    p[lane]      = (bf16)(xn1 * c - xn2 * sn);
    p[lane + 64] = (bf16)(xn2 * c + xn1 * sn);
}

// ---------------------------------------------------------------------------
// Flash attention, causal, GQA (q head h uses kv head h/4).
// BQ=BKV=64, 4 waves: wave owns 16 q rows, full D=128 accumulator.
// Output written IN PLACE into the q buffer. Plain staging. Finite masks.
// All buffers bf16 workspace.
// ---------------------------------------------------------------------------
__global__ __launch_bounds__(256)
void attn_fa(bf16* __restrict__ qob,        // [NTOK][QDIM], Q in / O out
             const bf16* __restrict__ kb,   // [NTOK][KVDIM]
             const bf16* __restrict__ vtb)  // [B][KVDIM][SEQ]  (V transposed)
{
    __shared__ bf16 sK [4*64*32];   // [kt][64 kv rows][32 hd]   16KB
    __shared__ bf16 sVt[2*128*32];  // [kt2][128 d rows][32 kv]  16KB
    __shared__ bf16 sP [2*64*32];   // [kt2][64 q rows][32 kv]    8KB

    const int tid  = threadIdx.x;
    const int wave = tid >> 6;
    const int lane = tid & 63;
    const int l15  = lane & 15;
    const int quad = lane >> 4;

    const int qt = blockIdx.x;      // q tile (32)
    const int h  = blockIdx.y;      // q head (32)
    const int b  = blockIdx.z;      // batch (2)
    const int hk = h >> 2;
    const int qbase = qt * 64;
    const int wq0   = wave * 16;

    // Q fragments straight from global (one-time, 16 rows per wave)
    bf16x8 aq[4];
    {
        const bf16* qrow = qob + (size_t)(b*SEQ + qbase + wq0 + l15)*QDIM + h*HD;
        #pragma unroll
        for (int kt = 0; kt < 4; ++kt)
            aq[kt] = *(const bf16x8*)(qrow + kt*32 + quad*8);
    }

    f32x4 oacc[8] = {};
    float m_i[4], l_i[4];
    #pragma unroll
    for (int r = 0; r < 4; ++r) { m_i[r] = NEGBIG; l_i[r] = 0.0f; }

    const float scale = 0.08838834764831845f;  // 1/sqrt(128)
    const int   nkv   = qt + 1;

    for (int kv = 0; kv < nkv; ++kv) {
        __syncthreads();
        // stage K tile: 64 rows x 128 dims -> sK[kt][row][32]
        {
            const int row = tid >> 2;          // 0..63
            const int c8  = (tid & 3) * 8;     // 0,8,16,24
            const bf16* g = kb + (size_t)(b*SEQ + kv*64 + row)*KVDIM + hk*HD;
            #pragma unroll
            for (int kt = 0; kt < 4; ++kt) {
                bf16x8 v = *(const bf16x8*)(g + kt*32 + c8);
                *(bf16x8*)(sK + kt*2048 + row*32 + c8) = v;
            }
        }
        // stage Vt tile: 128 d x 64 kv -> sVt[kvc>>5][d][kvc&31]
        {
            const int d  = tid >> 1;           // 0..127
            const int c8 = (tid & 1) * 8;      // 0,8
            const bf16* g = vtb + ((size_t)(b*NKV + hk)*HD + d)*SEQ + kv*64;
            #pragma unroll
            for (int i = 0; i < 4; ++i) {
                const int kvc = i*16 + c8;     // 0..56
                bf16x8 v = *(const bf16x8*)(g + kvc);
                *(bf16x8*)(sVt + (kvc>>5)*4096 + d*32 + (kvc & 31)) = v;
            }
        }
        __syncthreads();

        // S = Q K^T  (rows: wave's 16 q rows; cols: 64 kv)
        f32x4 s_acc[4];
        #pragma unroll
        for (int ni = 0; ni < 4; ++ni) {
            f32x4 z = {};
            #pragma unroll
            for (int kt = 0; kt < 4; ++kt) {
                bf16x8 bk = *(const bf16x8*)(sK + kt*2048 + (ni*16 + l15)*32 + quad*8);
                z = __builtin_amdgcn_mfma_f32_16x16x32_bf16(aq[kt], bk, z, 0, 0, 0);
            }
            s_acc[ni] = z;
        }

        // scale + causal mask (only the diagonal tile needs it); finite mask
        const int qrow0 = qbase + wq0 + quad*4;
        const bool diag = (kv == qt);
        #pragma unroll
        for (int ni = 0; ni < 4; ++ni) {
            const int kcol = kv*64 + ni*16 + l15;
            #pragma unroll
            for (int r = 0; r < 4; ++r) {
                float v = s_acc[ni][r] * scale;
                if (diag && kcol > qrow0 + r) v = NEGBIG;
                s_acc[ni][r] = v;
            }
        }

        // online softmax (rows live on 16-lane groups within each quad)
        float p[4][4], alpha[4];
        #pragma unroll
        for (int r = 0; r < 4; ++r) {
            float mx = fmaxf(fmaxf(s_acc[0][r], s_acc[1][r]),
                             fmaxf(s_acc[2][r], s_acc[3][r]));
            #pragma unroll
            for (int msk = 1; msk < 16; msk <<= 1)
                mx = fmaxf(mx, __shfl_xor(mx, msk));
            const float mnew = fmaxf(m_i[r], mx);
            alpha[r] = __expf(m_i[r] - mnew);   // finite-finite, in [0,1]
            m_i[r] = mnew;
            float sum = 0.0f;
            #pragma unroll
            for (int ni = 0; ni < 4; ++ni) {
                const float pv = __expf(s_acc[ni][r] - mnew);
                p[ni][r] = pv;
                sum += pv;
            }
            #pragma unroll
            for (int msk = 1; msk < 16; msk <<= 1)
                sum += __shfl_xor(sum, msk);
            l_i[r] = l_i[r]*alpha[r] + sum;
        }

        // rescale O
        #pragma unroll
        for (int di = 0; di < 8; ++di)
            #pragma unroll
            for (int r = 0; r < 4; ++r)
                oacc[di][r] *= alpha[r];

        // P: C-layout -> LDS -> A-layout (own wave's 16 rows only; in-wave
        // ds ordering is program order, no barrier needed)
        #pragma unroll
        for (int ni = 0; ni < 4; ++ni)
            #pragma unroll
            for (int r = 0; r < 4; ++r)
                sP[(ni>>1)*2048 + (wq0 + quad*4 + r)*32 + (ni&1)*16 + l15] =
                    (bf16)p[ni][r];

        bf16x8 ap[2];
        #pragma unroll
        for (int kt2 = 0; kt2 < 2; ++kt2)
            ap[kt2] = *(const bf16x8*)(sP + kt2*2048 + (wq0 + l15)*32 + quad*8);

        // O += P V   (B operand = V^T rows, i.e. d on lane&15)
        #pragma unroll
        for (int di = 0; di < 8; ++di)
            #pragma unroll
            for (int kt2 = 0; kt2 < 2; ++kt2) {
                bf16x8 bv = *(const bf16x8*)(sVt + kt2*4096 + (di*16 + l15)*32 + quad*8);
                oacc[di] = __builtin_amdgcn_mfma_f32_16x16x32_bf16(ap[kt2], bv, oacc[di], 0, 0, 0);
            }
    }

    // epilogue: O / l -> back into qob (in place)
    #pragma unroll
    for (int di = 0; di < 8; ++di) {
        const int col = h*HD + di*16 + l15;
        #pragma unroll
        for (int r = 0; r < 4; ++r) {
            const int row = b*SEQ + qbase + wq0 + quad*4 + r;
            qob[(size_t)row*QDIM + col] = (bf16)(oacc[di][r] / l_i[r]);
        }
    }
}

// ---------------------------------------------------------------------------
extern "C" void kernel_launch(void* const* d_in, const int* in_sizes, int n_in,
                              void* d_out, int out_size, void* d_ws, size_t ws_size,
                              hipStream_t stream)
{
    // fp32 inputs per the reference dtypes
    const float* hidden = (const float*)d_in[0];
    const int*   pos    = (const int*)d_in[1];
    const float* wq     = (const float*)d_in[2];
    const float* wk     = (const float*)d_in[3];
    const float* wv     = (const float*)d_in[4];
    const float* wo     = (const float*)d_in[5];
    const float* qw     = (const float*)d_in[6];
    const float* kw     = (const float*)d_in[7];

    // bf16 workspace: 32MB + 8MB + 8MB = 48MB total
    bf16* qbuf = (bf16*)d_ws;                         // [NTOK][QDIM]   32MB (Q, then attn out)
    bf16* kbuf = qbuf + (size_t)NTOK*QDIM;            // [NTOK][KVDIM]   8MB
    bf16* vtb  = kbuf + (size_t)NTOK*KVDIM;           // [B][KVDIM][SEQ] 8MB
    float* out = (float*)d_out;                       // fp32 output

    const dim3 blk(256);

    gemm_bt<true,true,false,false><<<dim3(QDIM/128,  NTOK/128), blk, 0, stream>>>(hidden, wq, qbuf, NTOK, QDIM,  HIDDEN);
    gemm_bt<true,true,false,false><<<dim3(KVDIM/128, NTOK/128), blk, 0, stream>>>(hidden, wk, kbuf, NTOK, KVDIM, HIDDEN);
    gemm_bt<true,true,true ,false><<<dim3(KVDIM/128, NTOK/128), blk, 0, stream>>>(hidden, wv, vtb,  NTOK, KVDIM, HIDDEN);

    ln_rope<<<dim3(NTOK*NH/4),  blk, 0, stream>>>(qbuf, qw, pos, NH);
    ln_rope<<<dim3(NTOK*NKV/4), blk, 0, stream>>>(kbuf, kw, pos, NKV);

    attn_fa<<<dim3(SEQ/64, NH, BATCH), blk, 0, stream>>>(qbuf, kbuf, vtb);

    gemm_bt<false,true,false,true><<<dim3(QDIM/128, NTOK/128), blk, 0, stream>>>(qbuf, wo, out, NTOK, QDIM, HIDDEN);
}

// Round 5
// 1170.244 us; speedup vs baseline: 1.2818x; 1.2818x over previous
//
#include <hip/hip_runtime.h>
#include <hip/hip_bf16.h>
#include <stdint.h>
#include <math.h>

typedef __bf16 bf16;
typedef __bf16 bf16x4 __attribute__((ext_vector_type(4)));
typedef __bf16 bf16x8 __attribute__((ext_vector_type(8)));
typedef float  f32x4  __attribute__((ext_vector_type(4)));

#define HIDDEN 4096
#define NH     32
#define NKV    8
#define HD     128
#define SEQ    2048
#define BATCH  2
#define NTOK   (BATCH*SEQ)   // 4096
#define QDIM   (NH*HD)       // 4096
#define KVDIM  (NKV*HD)      // 1024

#define NEGBIG (-3.0e38f)

__device__ __forceinline__ void gl_lds16(const bf16* g, bf16* l) {
    // async global->LDS, 16B/lane; LDS dest is wave-uniform base + lane*16
    __builtin_amdgcn_global_load_lds((__attribute__((address_space(1))) void*)g,
                                     (__attribute__((address_space(3))) void*)l,
                                     16, 0, 0);
}

// ---------------------------------------------------------------------------
// fp32 -> bf16 bulk convert, 8 elem/thread (two f32x4 loads, one 16B store)
// ---------------------------------------------------------------------------
__global__ __launch_bounds__(256)
void cvt_f32_bf16(const float* __restrict__ src, bf16* __restrict__ dst)
{
    const size_t i = ((size_t)blockIdx.x * 256 + threadIdx.x) * 8;
    f32x4 f0 = *(const f32x4*)(src + i);
    f32x4 f1 = *(const f32x4*)(src + i + 4);
    bf16x8 o;
    #pragma unroll
    for (int j = 0; j < 4; ++j) { o[j] = (bf16)f0[j]; o[4+j] = (bf16)f1[j]; }
    *(bf16x8*)(dst + i) = o;
}

// ---------------------------------------------------------------------------
// GEMM: C[m][n] = sum_k A[m][k] * B[n][k]   (A,B bf16 row-major, B^T input)
// m97 pattern: 128x128 tile, BK=32, 4 waves 2x2, global_load_lds width=16,
// mfma_f32_16x16x32_bf16.
// TRANSV: write C^T in vt layout [b][col][s].  F32OUT: C written fp32.
// ---------------------------------------------------------------------------
template<bool TRANSV, bool F32OUT>
__global__ __launch_bounds__(256)
void gemm_bt(const bf16* __restrict__ A, const bf16* __restrict__ B,
             void* __restrict__ Cv, int M, int N, int K)
{
    __shared__ bf16 sA[128*32];
    __shared__ bf16 sB[128*32];

    const int tid  = threadIdx.x;
    const int wave = tid >> 6;
    const int lane = tid & 63;
    const int l15  = lane & 15;
    const int quad = lane >> 4;
    const int m_blk = blockIdx.y * 128;
    const int n_blk = blockIdx.x * 128;
    const int wm = (wave >> 1) * 64;
    const int wn = (wave & 1) * 64;

    f32x4 acc[4][4] = {};

    const int rowInSeg = lane >> 2;        // 0..15
    const int colInSeg = (lane & 3) * 8;   // 0,8,16,24

    for (int k0 = 0; k0 < K; k0 += 32) {
        __syncthreads();   // previous iteration's readers done
        #pragma unroll
        for (int i = 0; i < 2; ++i) {
            int s = wave * 2 + i;          // 8 segments of 16 rows each
            const bf16* ga = A + (size_t)(m_blk + s*16 + rowInSeg) * K + k0 + colInSeg;
            gl_lds16(ga, sA + s*512);
            const bf16* gb = B + (size_t)(n_blk + s*16 + rowInSeg) * K + k0 + colInSeg;
            gl_lds16(gb, sB + s*512);
        }
        __syncthreads();   // drains vmcnt(0) before barrier -> data landed

        bf16x8 af[4], bfr[4];
        #pragma unroll
        for (int mi = 0; mi < 4; ++mi)
            af[mi] = *(const bf16x8*)(sA + (wm + mi*16 + l15)*32 + quad*8);
        #pragma unroll
        for (int ni = 0; ni < 4; ++ni)
            bfr[ni] = *(const bf16x8*)(sB + (wn + ni*16 + l15)*32 + quad*8);
        #pragma unroll
        for (int mi = 0; mi < 4; ++mi)
            #pragma unroll
            for (int ni = 0; ni < 4; ++ni)
                acc[mi][ni] = __builtin_amdgcn_mfma_f32_16x16x32_bf16(
                                  af[mi], bfr[ni], acc[mi][ni], 0, 0, 0);
    }

    #pragma unroll
    for (int mi = 0; mi < 4; ++mi) {
        #pragma unroll
        for (int ni = 0; ni < 4; ++ni) {
            const int col = n_blk + wn + ni*16 + l15;
            if constexpr (TRANSV) {
                const int row0 = m_blk + wm + mi*16 + quad*4;
                const int bb = row0 >> 11;          // /SEQ
                const int ss = row0 & (SEQ - 1);
                bf16x4 pk;
                #pragma unroll
                for (int r = 0; r < 4; ++r) pk[r] = (bf16)acc[mi][ni][r];
                *(bf16x4*)((bf16*)Cv + ((size_t)bb * KVDIM + col) * SEQ + ss) = pk;
            } else if constexpr (F32OUT) {
                #pragma unroll
                for (int r = 0; r < 4; ++r) {
                    const int row = m_blk + wm + mi*16 + quad*4 + r;
                    ((float*)Cv)[(size_t)row * N + col] = acc[mi][ni][r];
                }
            } else {
                #pragma unroll
                for (int r = 0; r < 4; ++r) {
                    const int row = m_blk + wm + mi*16 + quad*4 + r;
                    ((bf16*)Cv)[(size_t)row * N + col] = (bf16)acc[mi][ni][r];
                }
            }
        }
    }
}

// ---------------------------------------------------------------------------
// Per-head LayerNorm + RoPE, in place on bf16 workspace. One wave per
// (token, head); lane j holds dims j and j+64 (the RoPE pair). w is fp32.
// ---------------------------------------------------------------------------
__global__ __launch_bounds__(256)
void ln_rope(bf16* __restrict__ buf, const float* __restrict__ w,
             const int* __restrict__ pos, int nh)
{
    const int id   = blockIdx.x * 4 + (threadIdx.x >> 6);
    const int lane = threadIdx.x & 63;
    const int t  = id / nh;
    const int hh = id - t * nh;

    bf16* p = buf + (size_t)t * nh * HD + hh * HD;
    float x1 = (float)p[lane];
    float x2 = (float)p[lane + 64];

    float s1 = x1 + x2, s2 = x1*x1 + x2*x2;
    #pragma unroll
    for (int m = 1; m < 64; m <<= 1) {
        s1 += __shfl_xor(s1, m);
        s2 += __shfl_xor(s2, m);
    }
    const float mean = s1 * (1.0f/128.0f);
    const float var  = s2 * (1.0f/128.0f) - mean*mean;
    const float rs   = rsqrtf(fmaxf(var, 0.0f) + 1e-5f);

    const float w1 = w[hh*HD + lane];
    const float w2 = w[hh*HD + lane + 64];
    const float xn1 = (x1 - mean) * rs * w1;
    const float xn2 = (x2 - mean) * rs * w2;

    const int s = t & (SEQ - 1);
    // inv_freq = 10000^(-lane/64) = exp(-lane * ln(10000)/64)
    const float ang = (float)pos[s] * __expf(-(float)lane * (9.210340371976184f/64.0f));
    const float c = cosf(ang), sn = sinf(ang);

    p[lane]      = (bf16)(xn1 * c - xn2 * sn);
    p[lane + 64] = (bf16)(xn2 * c + xn1 * sn);
}

// ---------------------------------------------------------------------------
// Flash attention, causal, GQA (q head h uses kv head h/4).
// BQ=BKV=64, 4 waves: wave owns 16 q rows, full D=128 accumulator.
// Output written IN PLACE into the q buffer. Plain staging. Finite masks.
// ---------------------------------------------------------------------------
__global__ __launch_bounds__(256)
void attn_fa(bf16* __restrict__ qob,        // [NTOK][QDIM], Q in / O out
             const bf16* __restrict__ kb,   // [NTOK][KVDIM]
             const bf16* __restrict__ vtb)  // [B][KVDIM][SEQ]  (V transposed)
{
    __shared__ bf16 sK [4*64*32];   // [kt][64 kv rows][32 hd]   16KB
    __shared__ bf16 sVt[2*128*32];  // [kt2][128 d rows][32 kv]  16KB
    __shared__ bf16 sP [2*64*32];   // [kt2][64 q rows][32 kv]    8KB

    const int tid  = threadIdx.x;
    const int wave = tid >> 6;
    const int lane = tid & 63;
    const int l15  = lane & 15;
    const int quad = lane >> 4;

    const int qt = blockIdx.x;      // q tile (32)
    const int h  = blockIdx.y;      // q head (32)
    const int b  = blockIdx.z;      // batch (2)
    const int hk = h >> 2;
    const int qbase = qt * 64;
    const int wq0   = wave * 16;

    // Q fragments straight from global (one-time, 16 rows per wave)
    bf16x8 aq[4];
    {
        const bf16* qrow = qob + (size_t)(b*SEQ + qbase + wq0 + l15)*QDIM + h*HD;
        #pragma unroll
        for (int kt = 0; kt < 4; ++kt)
            aq[kt] = *(const bf16x8*)(qrow + kt*32 + quad*8);
    }

    f32x4 oacc[8] = {};
    float m_i[4], l_i[4];
    #pragma unroll
    for (int r = 0; r < 4; ++r) { m_i[r] = NEGBIG; l_i[r] = 0.0f; }

    const float scale = 0.08838834764831845f;  // 1/sqrt(128)
    const int   nkv   = qt + 1;

    for (int kv = 0; kv < nkv; ++kv) {
        __syncthreads();
        // stage K tile: 64 rows x 128 dims -> sK[kt][row][32]
        {
            const int row = tid >> 2;          // 0..63
            const int c8  = (tid & 3) * 8;     // 0,8,16,24
            const bf16* g = kb + (size_t)(b*SEQ + kv*64 + row)*KVDIM + hk*HD;
            #pragma unroll
            for (int kt = 0; kt < 4; ++kt) {
                bf16x8 v = *(const bf16x8*)(g + kt*32 + c8);
                *(bf16x8*)(sK + kt*2048 + row*32 + c8) = v;
            }
        }
        // stage Vt tile: 128 d x 64 kv -> sVt[kvc>>5][d][kvc&31]
        {
            const int d  = tid >> 1;           // 0..127
            const int c8 = (tid & 1) * 8;      // 0,8
            const bf16* g = vtb + ((size_t)(b*NKV + hk)*HD + d)*SEQ + kv*64;
            #pragma unroll
            for (int i = 0; i < 4; ++i) {
                const int kvc = i*16 + c8;     // 0..56
                bf16x8 v = *(const bf16x8*)(g + kvc);
                *(bf16x8*)(sVt + (kvc>>5)*4096 + d*32 + (kvc & 31)) = v;
            }
        }
        __syncthreads();

        // S = Q K^T  (rows: wave's 16 q rows; cols: 64 kv)
        f32x4 s_acc[4];
        #pragma unroll
        for (int ni = 0; ni < 4; ++ni) {
            f32x4 z = {};
            #pragma unroll
            for (int kt = 0; kt < 4; ++kt) {
                bf16x8 bk = *(const bf16x8*)(sK + kt*2048 + (ni*16 + l15)*32 + quad*8);
                z = __builtin_amdgcn_mfma_f32_16x16x32_bf16(aq[kt], bk, z, 0, 0, 0);
            }
            s_acc[ni] = z;
        }

        // scale + causal mask (only the diagonal tile needs it); finite mask
        const int qrow0 = qbase + wq0 + quad*4;
        const bool diag = (kv == qt);
        #pragma unroll
        for (int ni = 0; ni < 4; ++ni) {
            const int kcol = kv*64 + ni*16 + l15;
            #pragma unroll
            for (int r = 0; r < 4; ++r) {
                float v = s_acc[ni][r] * scale;
                if (diag && kcol > qrow0 + r) v = NEGBIG;
                s_acc[ni][r] = v;
            }
        }

        // online softmax (rows live on 16-lane groups within each quad)
        float p[4][4], alpha[4];
        #pragma unroll
        for (int r = 0; r < 4; ++r) {
            float mx = fmaxf(fmaxf(s_acc[0][r], s_acc[1][r]),
                             fmaxf(s_acc[2][r], s_acc[3][r]));
            #pragma unroll
            for (int msk = 1; msk < 16; msk <<= 1)
                mx = fmaxf(mx, __shfl_xor(mx, msk));
            const float mnew = fmaxf(m_i[r], mx);
            alpha[r] = __expf(m_i[r] - mnew);   // finite-finite, in [0,1]
            m_i[r] = mnew;
            float sum = 0.0f;
            #pragma unroll
            for (int ni = 0; ni < 4; ++ni) {
                const float pv = __expf(s_acc[ni][r] - mnew);
                p[ni][r] = pv;
                sum += pv;
            }
            #pragma unroll
            for (int msk = 1; msk < 16; msk <<= 1)
                sum += __shfl_xor(sum, msk);
            l_i[r] = l_i[r]*alpha[r] + sum;
        }

        // rescale O
        #pragma unroll
        for (int di = 0; di < 8; ++di)
            #pragma unroll
            for (int r = 0; r < 4; ++r)
                oacc[di][r] *= alpha[r];

        // P: C-layout -> LDS -> A-layout (own wave's 16 rows only)
        #pragma unroll
        for (int ni = 0; ni < 4; ++ni)
            #pragma unroll
            for (int r = 0; r < 4; ++r)
                sP[(ni>>1)*2048 + (wq0 + quad*4 + r)*32 + (ni&1)*16 + l15] =
                    (bf16)p[ni][r];

        bf16x8 ap[2];
        #pragma unroll
        for (int kt2 = 0; kt2 < 2; ++kt2)
            ap[kt2] = *(const bf16x8*)(sP + kt2*2048 + (wq0 + l15)*32 + quad*8);

        // O += P V   (B operand = V^T rows, i.e. d on lane&15)
        #pragma unroll
        for (int di = 0; di < 8; ++di)
            #pragma unroll
            for (int kt2 = 0; kt2 < 2; ++kt2) {
                bf16x8 bv = *(const bf16x8*)(sVt + kt2*4096 + (di*16 + l15)*32 + quad*8);
                oacc[di] = __builtin_amdgcn_mfma_f32_16x16x32_bf16(ap[kt2], bv, oacc[di], 0, 0, 0);
            }
    }

    // epilogue: O / l -> back into qob (in place)
    #pragma unroll
    for (int di = 0; di < 8; ++di) {
        const int col = h*HD + di*16 + l15;
        #pragma unroll
        for (int r = 0; r < 4; ++r) {
            const int row = b*SEQ + qbase + wq0 + quad*4 + r;
            qob[(size_t)row*QDIM + col] = (bf16)(oacc[di][r] / l_i[r]);
        }
    }
}

// ---------------------------------------------------------------------------
extern "C" void kernel_launch(void* const* d_in, const int* in_sizes, int n_in,
                              void* d_out, int out_size, void* d_ws, size_t ws_size,
                              hipStream_t stream)
{
    // fp32 inputs per the reference dtypes
    const float* hidden = (const float*)d_in[0];
    const int*   pos    = (const int*)d_in[1];
    const float* wq     = (const float*)d_in[2];
    const float* wk     = (const float*)d_in[3];
    const float* wv     = (const float*)d_in[4];
    const float* wo     = (const float*)d_in[5];
    const float* qw     = (const float*)d_in[6];
    const float* kw     = (const float*)d_in[7];

    // bf16 workspace, 128 MB total (wo reuses the dead wq slot)
    bf16* hb   = (bf16*)d_ws;                          // [NTOK][HIDDEN]  32MB
    bf16* wqb  = hb   + (size_t)NTOK*HIDDEN;           // [QDIM][HIDDEN]  32MB (wq, then wo)
    bf16* wkb  = wqb  + (size_t)QDIM*HIDDEN;           // [KVDIM][HIDDEN]  8MB
    bf16* wvb  = wkb  + (size_t)KVDIM*HIDDEN;          // [KVDIM][HIDDEN]  8MB
    bf16* qbuf = wvb  + (size_t)KVDIM*HIDDEN;          // [NTOK][QDIM]    32MB (Q, then attn out)
    bf16* kbuf = qbuf + (size_t)NTOK*QDIM;             // [NTOK][KVDIM]    8MB
    bf16* vtb  = kbuf + (size_t)NTOK*KVDIM;            // [B][KVDIM][SEQ]  8MB
    float* out = (float*)d_out;                        // fp32 output

    const dim3 blk(256);

    // fp32 -> bf16 pre-conversion (each size divisible by 2048)
    cvt_f32_bf16<<<dim3(NTOK*HIDDEN/2048),  blk, 0, stream>>>(hidden, hb);
    cvt_f32_bf16<<<dim3(QDIM*HIDDEN/2048),  blk, 0, stream>>>(wq, wqb);
    cvt_f32_bf16<<<dim3(KVDIM*HIDDEN/2048), blk, 0, stream>>>(wk, wkb);
    cvt_f32_bf16<<<dim3(KVDIM*HIDDEN/2048), blk, 0, stream>>>(wv, wvb);

    gemm_bt<false,false><<<dim3(QDIM/128,  NTOK/128), blk, 0, stream>>>(hb, wqb, qbuf, NTOK, QDIM,  HIDDEN);
    gemm_bt<false,false><<<dim3(KVDIM/128, NTOK/128), blk, 0, stream>>>(hb, wkb, kbuf, NTOK, KVDIM, HIDDEN);
    gemm_bt<true ,false><<<dim3(KVDIM/128, NTOK/128), blk, 0, stream>>>(hb, wvb, vtb,  NTOK, KVDIM, HIDDEN);

    // wq slot is dead after the Q-GEMM; stream order makes this safe
    cvt_f32_bf16<<<dim3(QDIM*HIDDEN/2048), blk, 0, stream>>>(wo, wqb);

    ln_rope<<<dim3(NTOK*NH/4),  blk, 0, stream>>>(qbuf, qw, pos, NH);
    ln_rope<<<dim3(NTOK*NKV/4), blk, 0, stream>>>(kbuf, kw, pos, NKV);

    attn_fa<<<dim3(SEQ/64, NH, BATCH), blk, 0, stream>>>(qbuf, kbuf, vtb);

    gemm_bt<false,true><<<dim3(QDIM/128, NTOK/128), blk, 0, stream>>>(qbuf, wqb, out, NTOK, QDIM, HIDDEN);
}